// Round 9
// baseline (216.841 us; speedup 1.0000x reference)
//
#include <hip/hip_runtime.h>
#include <stdint.h>

#define BSz 4096   // B*S tokens
#define Ddim 1024
#define Fdim 4096
#define Edim 4
#define Rdim 4

typedef __attribute__((ext_vector_type(8))) short bf16x8;
typedef __attribute__((ext_vector_type(4))) float f32x4;

__device__ __forceinline__ unsigned short f2bf(float f) {
  union { float f; uint32_t u; } c; c.f = f;
  return (unsigned short)((c.u + 0x7fffu + ((c.u >> 16) & 1u)) >> 16);
}

// ---------------- zero d_out (deterministic base for split-K atomics) ----
__global__ __launch_bounds__(256) void zero_f32(float* __restrict__ p, int n4) {
  int i = blockIdx.x * 256 + threadIdx.x;
  if (i < n4) ((float4*)p)[i] = make_float4(0.f, 0.f, 0.f, 0.f);
}

// ---------------- fp32 -> bf16 conversion (vectorized) ----------------
__global__ __launch_bounds__(256) void cvt_kernel(const float* __restrict__ in,
                                                  unsigned short* __restrict__ out,
                                                  int n4) {
  int i = blockIdx.x * 256 + threadIdx.x;
  if (i < n4) {
    float4 v = ((const float4*)in)[i];
    ushort4 o;
    o.x = f2bf(v.x); o.y = f2bf(v.y); o.z = f2bf(v.z); o.w = f2bf(v.w);
    ((ushort4*)out)[i] = o;
  }
}

// ---------------- router: logits -> softmax -> top2 + lora_low ----------------
__global__ __launch_bounds__(256) void router_kernel(const float* __restrict__ x,
                                                     const float* __restrict__ Wg,
                                                     const float* __restrict__ bg,
                                                     const float* __restrict__ Aw,
                                                     float* __restrict__ meta) {
  __shared__ float xs[Ddim];
  __shared__ float dots[Edim + Edim * Rdim];
  const int t = blockIdx.x;
  const float4* xt = (const float4*)(x + (size_t)t * Ddim);
  for (int i = threadIdx.x; i < Ddim / 4; i += 256) ((float4*)xs)[i] = xt[i];
  __syncthreads();
  const int wave = threadIdx.x >> 6, lane = threadIdx.x & 63;
  for (int d = wave * 5; d < wave * 5 + 5; ++d) {
    const float* wrow = (d < Edim) ? (Wg + (size_t)d * Ddim)
                                   : (Aw + (size_t)(d - Edim) * Ddim);
    float s = 0.f;
    for (int i = lane; i < Ddim; i += 64) s += xs[i] * wrow[i];
    for (int off = 32; off; off >>= 1) s += __shfl_down(s, off);
    if (lane == 0) dots[d] = s;
  }
  __syncthreads();
  if (threadIdx.x == 0) {
    float p[Edim];
    float m = -1e30f;
    for (int e = 0; e < Edim; ++e) { p[e] = dots[e] + bg[e]; m = fmaxf(m, p[e]); }
    float sum = 0.f;
    for (int e = 0; e < Edim; ++e) { p[e] = expf(p[e] - m); sum += p[e]; }
    const float inv = 1.f / sum;
    for (int e = 0; e < Edim; ++e) p[e] *= inv;
    int e0 = 0;
    for (int e = 1; e < Edim; ++e) if (p[e] > p[e0]) e0 = e;
    int e1 = (e0 == 0) ? 1 : 0;
    for (int e = 0; e < Edim; ++e) if (e != e0 && p[e] > p[e1]) e1 = e;
    float* mt = meta + (size_t)t * 16;
    mt[0] = (float)e0; mt[1] = (float)e1; mt[2] = p[e0]; mt[3] = p[e1];
    for (int r = 0; r < Rdim; ++r) {
      mt[4 + r] = dots[Edim + e0 * Rdim + r];
      mt[8 + r] = dots[Edim + e1 * Rdim + r];
    }
    mt[12] = 0.f; mt[13] = 0.f; mt[14] = 0.f; mt[15] = 0.f;
  }
}

// ---------------- m97-EXACT NT bf16 GEMM (linear source, linear LDS) --------
// C[M,N] = A[M,K] rows bm.. * B[N,K]^T rows bn.. over K-slice [kbase,+kslice).
// 128x128 tile, BK=64, 4 waves (2x2), single-buffered 32KB LDS, plain
// __syncthreads, LINEAR global source + LINEAR LDS reads (m97-exact; the
// 16-way read bank conflict is known-benign at this structure: m97=874TF
// with 1.7e7 conflicts; our R6 source-swizzle variant was 2x slower ->
// swizzled source breaks gload_lds coalescing). ~3 blocks/CU for TLP.
// EPI==0: fused MoE epilogue -> outg bf16 (LDS-repacked coalesced stores).
// EPI==1: f32 atomicAdd into outf (split-K).
template <int EPI>
__global__ __launch_bounds__(256, 3)
void gemm97(const unsigned short* __restrict__ Ag,
            const unsigned short* __restrict__ Bg,
            int K, int kslice, int Ncols,
            const float* __restrict__ meta,
            const float* __restrict__ B2,
            unsigned short* __restrict__ outg,
            float* __restrict__ outf) {
  constexpr int BK = 64;
  __shared__ __align__(16) unsigned short sA[128 * BK];   // 16 KB
  __shared__ __align__(16) unsigned short sB[128 * BK];   // 16 KB

  const int tid = threadIdx.x;
  const int lane = tid & 63;
  const int wave = tid >> 6;            // 0..3
  const int wr = wave >> 1, wc = wave & 1;
  const int l16 = lane & 15, lhi = lane >> 4;

  // XCD-aware bijective swizzle on the xy grid (nwg per z-slice % 8 == 0)
  const int nwg = gridDim.x * gridDim.y;
  const int lin = blockIdx.y * gridDim.x + blockIdx.x;
  const int cpx = nwg >> 3;
  const int swz = (lin & 7) * cpx + (lin >> 3);
  const int bx = swz % gridDim.x, by = swz / gridDim.x;
  const int bm = by * 128, bn = bx * 128;
  const int kbase = blockIdx.z * kslice;
  const int NT = kslice / BK;

  f32x4 acc[4][4] = {};

  // staging: LINEAR source, LINEAR dest. Round rr covers rows tid/8 + rr*32.
  const int srow = tid >> 3;                                  // 0..31
  const int scol = (tid & 7) * 8;                             // linear col
  const int ldst = tid * 8;                                   // linear LDS elems

  for (int kt = 0; kt < NT; ++kt) {
    const int kof = kbase + kt * BK;
#pragma unroll
    for (int rr = 0; rr < 4; ++rr)
      __builtin_amdgcn_global_load_lds(
          (const __attribute__((address_space(1))) void*)(Ag + (size_t)(bm + srow + rr * 32) * K + kof + scol),
          (__attribute__((address_space(3))) void*)(sA + ldst + rr * 2048), 16, 0, 0);
#pragma unroll
    for (int rr = 0; rr < 4; ++rr)
      __builtin_amdgcn_global_load_lds(
          (const __attribute__((address_space(1))) void*)(Bg + (size_t)(bn + srow + rr * 32) * K + kof + scol),
          (__attribute__((address_space(3))) void*)(sB + ldst + rr * 2048), 16, 0, 0);
    __syncthreads();
#pragma unroll
    for (int kk = 0; kk < 2; ++kk) {
      bf16x8 af[4], bfv[4];
#pragma unroll
      for (int i = 0; i < 4; ++i) {
        af[i] = *(const bf16x8*)(sA + (wr * 64 + i * 16 + l16) * BK + kk * 32 + lhi * 8);
        bfv[i] = *(const bf16x8*)(sB + (wc * 64 + i * 16 + l16) * BK + kk * 32 + lhi * 8);
      }
#pragma unroll
      for (int i = 0; i < 4; ++i)
#pragma unroll
        for (int j = 0; j < 4; ++j)
          acc[i][j] = __builtin_amdgcn_mfma_f32_16x16x32_bf16(af[i], bfv[j], acc[i][j], 0, 0, 0);
    }
    __syncthreads();
  }

  if (EPI == 0) {
    // fused MoE epilogue: gv = sum_{e in top2} w_e*relu(acc + <ll_e,B2[e,f,:]>)
    // repack through LDS (sA rows 0..63, sB rows 64..127) -> coalesced stores.
#pragma unroll
    for (int mi = 0; mi < 4; ++mi) {
#pragma unroll
      for (int r = 0; r < 4; ++r) {
        const int rowl = wr * 64 + mi * 16 + lhi * 4 + r;     // 0..127
        const int row = bm + rowl;
        const float* mt = meta + (size_t)row * 16;
        const int e0 = (int)mt[0], e1 = (int)mt[1];
        const float w0 = mt[2], w1 = mt[3];
        const float4 l0 = *(const float4*)(mt + 4);
        const float4 l1 = *(const float4*)(mt + 8);
        unsigned short* trow = (rowl < 64 ? sA + rowl * 128 : sB + (rowl - 64) * 128);
#pragma unroll
        for (int ni = 0; ni < 4; ++ni) {
          const int coll = wc * 64 + ni * 16 + l16;
          const int f = bn + coll;
          const float4 b0 = *(const float4*)(B2 + ((size_t)e0 * Fdim + f) * Rdim);
          const float4 b1 = *(const float4*)(B2 + ((size_t)e1 * Fdim + f) * Rdim);
          const float a = acc[mi][ni][r];
          const float lora0 = l0.x * b0.x + l0.y * b0.y + l0.z * b0.z + l0.w * b0.w;
          const float lora1 = l1.x * b1.x + l1.y * b1.y + l1.z * b1.z + l1.w * b1.w;
          const float gv = w0 * fmaxf(a + lora0, 0.f) + w1 * fmaxf(a + lora1, 0.f);
          trow[coll] = f2bf(gv);
        }
      }
    }
    __syncthreads();
    // coalesced copy: 128 rows x 256B; 16 threads/row x 16B; 8 rounds.
#pragma unroll
    for (int rnd = 0; rnd < 8; ++rnd) {
      const int idx = rnd * 256 + tid;          // 0..2047
      const int rowl = idx >> 4;                // 0..127
      const int chk = idx & 15;                 // 16B chunk
      const unsigned short* src = (rowl < 64 ? sA + rowl * 128 : sB + (rowl - 64) * 128) + chk * 8;
      *(bf16x8*)(outg + (size_t)(bm + rowl) * Fdim + bn + chk * 8) = *(const bf16x8*)src;
    }
  } else {
    // split-K partial: f32 atomic accumulate (16 lanes x 4B = 64B sectors)
#pragma unroll
    for (int mi = 0; mi < 4; ++mi)
#pragma unroll
      for (int ni = 0; ni < 4; ++ni)
#pragma unroll
        for (int r = 0; r < 4; ++r) {
          const int row = bm + wr * 64 + mi * 16 + lhi * 4 + r;
          const int col = bn + wc * 64 + ni * 16 + l16;
          unsafeAtomicAdd(&outf[(size_t)row * Ncols + col], acc[mi][ni][r]);
        }
  }
}

extern "C" void kernel_launch(void* const* d_in, const int* in_sizes, int n_in,
                              void* d_out, int out_size, void* d_ws, size_t ws_size,
                              hipStream_t stream) {
  const float* x  = (const float*)d_in[0];
  const float* Wg = (const float*)d_in[1];
  const float* bg = (const float*)d_in[2];
  const float* Wi = (const float*)d_in[3];
  const float* Wo = (const float*)d_in[4];
  const float* Aw = (const float*)d_in[5];
  const float* B2 = (const float*)d_in[6];
  float* out = (float*)d_out;

  // workspace layout (bf16 as ushort)
  unsigned short* xb  = (unsigned short*)d_ws;                 // [BSz][Ddim]   8 MB
  unsigned short* wib = xb  + (size_t)BSz  * Ddim;             // [Fdim][Ddim]  8 MB
  unsigned short* wob = wib + (size_t)Fdim * Ddim;             // [Ddim][Fdim]  8 MB
  unsigned short* g   = wob + (size_t)Ddim * Fdim;             // [BSz][Fdim]  32 MB
  float* meta = (float*)(g + (size_t)BSz * Fdim);              // [BSz][16]   256 KB

  zero_f32<<<BSz * Ddim / 4 / 256, 256, 0, stream>>>(out, BSz * Ddim / 4);

  const int n4x = BSz * Ddim / 4;   // == Fdim*Ddim/4 == Ddim*Fdim/4
  cvt_kernel<<<(n4x + 255) / 256, 256, 0, stream>>>(x,  xb,  n4x);
  cvt_kernel<<<(n4x + 255) / 256, 256, 0, stream>>>(Wi, wib, n4x);
  cvt_kernel<<<(n4x + 255) / 256, 256, 0, stream>>>(Wo, wob, n4x);

  router_kernel<<<BSz, 256, 0, stream>>>(x, Wg, bg, Aw, meta);

  // GEMM1: base = x * Wi^T, fused MoE epilogue -> g (bf16)
  // 128^2 tile, grid 32x32 = 1024 blocks (~3/CU co-resident), K=1024
  gemm97<0><<<dim3(Fdim / 128, BSz / 128, 1), 256, 0, stream>>>(
      xb, wib, Ddim, Ddim, Fdim, meta, B2, g, nullptr);

  // GEMM2: out = g * Wo^T, split-K x4 (slices of 1024), f32 atomics
  // grid 8x32x4 = 1024 blocks (~3/CU)
  gemm97<1><<<dim3(Ddim / 128, BSz / 128, 4), 256, 0, stream>>>(
      g, wob, Fdim, Fdim / 4, Ddim, nullptr, nullptr, nullptr, out);
}

// Round 10
// 195.997 us; speedup vs baseline: 1.1063x; 1.1063x over previous
//
#include <hip/hip_runtime.h>
#include <stdint.h>

#define BSz 4096   // B*S tokens
#define Ddim 1024
#define Fdim 4096
#define Edim 4
#define Rdim 4

typedef __attribute__((ext_vector_type(8))) short bf16x8;
typedef __attribute__((ext_vector_type(4))) float f32x4;

__device__ __forceinline__ unsigned short f2bf(float f) {
  union { float f; uint32_t u; } c; c.f = f;
  return (unsigned short)((c.u + 0x7fffu + ((c.u >> 16) & 1u)) >> 16);
}

// asm ds_read_b128: opaque to SIInsertWaitcnts (no auto vmcnt(0) before it).
// Caller must lgkmcnt(0) + sched_barrier(0) before consuming (rule 18).
__device__ __forceinline__ bf16x8 ldsr128(const unsigned short* p) {
  bf16x8 r;
  unsigned a = (unsigned)(uintptr_t)(const __attribute__((address_space(3))) void*)p;
  asm volatile("ds_read_b128 %0, %1" : "=v"(r) : "v"(a));
  return r;
}

// ---------------- zero d_out (deterministic base for split-K atomics) ----
__global__ __launch_bounds__(256) void zero_f32(float* __restrict__ p, int n4) {
  int i = blockIdx.x * 256 + threadIdx.x;
  if (i < n4) ((float4*)p)[i] = make_float4(0.f, 0.f, 0.f, 0.f);
}

// ---------------- fp32 -> bf16 conversion (vectorized) ----------------
__global__ __launch_bounds__(256) void cvt_kernel(const float* __restrict__ in,
                                                  unsigned short* __restrict__ out,
                                                  int n4) {
  int i = blockIdx.x * 256 + threadIdx.x;
  if (i < n4) {
    float4 v = ((const float4*)in)[i];
    ushort4 o;
    o.x = f2bf(v.x); o.y = f2bf(v.y); o.z = f2bf(v.z); o.w = f2bf(v.w);
    ((ushort4*)out)[i] = o;
  }
}

// ---------------- router: logits -> softmax -> top2 + lora_low ----------------
__global__ __launch_bounds__(256) void router_kernel(const float* __restrict__ x,
                                                     const float* __restrict__ Wg,
                                                     const float* __restrict__ bg,
                                                     const float* __restrict__ Aw,
                                                     float* __restrict__ meta) {
  __shared__ float xs[Ddim];
  __shared__ float dots[Edim + Edim * Rdim];
  const int t = blockIdx.x;
  const float4* xt = (const float4*)(x + (size_t)t * Ddim);
  for (int i = threadIdx.x; i < Ddim / 4; i += 256) ((float4*)xs)[i] = xt[i];
  __syncthreads();
  const int wave = threadIdx.x >> 6, lane = threadIdx.x & 63;
  for (int d = wave * 5; d < wave * 5 + 5; ++d) {
    const float* wrow = (d < Edim) ? (Wg + (size_t)d * Ddim)
                                   : (Aw + (size_t)(d - Edim) * Ddim);
    float s = 0.f;
    for (int i = lane; i < Ddim; i += 64) s += xs[i] * wrow[i];
    for (int off = 32; off; off >>= 1) s += __shfl_down(s, off);
    if (lane == 0) dots[d] = s;
  }
  __syncthreads();
  if (threadIdx.x == 0) {
    float p[Edim];
    float m = -1e30f;
    for (int e = 0; e < Edim; ++e) { p[e] = dots[e] + bg[e]; m = fmaxf(m, p[e]); }
    float sum = 0.f;
    for (int e = 0; e < Edim; ++e) { p[e] = expf(p[e] - m); sum += p[e]; }
    const float inv = 1.f / sum;
    for (int e = 0; e < Edim; ++e) p[e] *= inv;
    int e0 = 0;
    for (int e = 1; e < Edim; ++e) if (p[e] > p[e0]) e0 = e;
    int e1 = (e0 == 0) ? 1 : 0;
    for (int e = 0; e < Edim; ++e) if (e != e0 && p[e] > p[e1]) e1 = e;
    float* mt = meta + (size_t)t * 16;
    mt[0] = (float)e0; mt[1] = (float)e1; mt[2] = p[e0]; mt[3] = p[e1];
    for (int r = 0; r < Rdim; ++r) {
      mt[4 + r] = dots[Edim + e0 * Rdim + r];
      mt[8 + r] = dots[Edim + e1 * Rdim + r];
    }
    mt[12] = 0.f; mt[13] = 0.f; mt[14] = 0.f; mt[15] = 0.f;
  }
}

// ------------- ring-4 deep-pipelined 256x256 NT bf16 GEMM -----------------
// C[M,N] = A[M,K] rows bm.. * B[N,K]^T rows bn.. over K-slice [kbase,+1024).
// BK=32, 4-slot LDS ring (4 x (A 16KB + B 16KB) = 128 KB), 8 waves (2Mx4N).
// Tile t+3 staged during tile t -> issue->consume lag ~3 tiles (>HBM lat).
// vmcnt(8) once per tile retires exactly tile t's 4 loads/thread, leaving
// t+1/t+2 in flight. 2 raw barriers/tile; asm ds_read (no compiler vmcnt(0)).
// XOR chunk swizzle (chunk ^ row&3) via pre-swizzled source + swizzled read.
// EPI==0: fused MoE epilogue -> outg bf16 (LDS repack).  EPI==1: f32 atomics.
template <int EPI>
__global__ __launch_bounds__(512, 1)
void gemmring(const unsigned short* __restrict__ Ag,
              const unsigned short* __restrict__ Bg,
              int K, int Ncols,
              const float* __restrict__ meta,
              const float* __restrict__ B2,
              unsigned short* __restrict__ outg,
              float* __restrict__ outf) {
  constexpr int BK = 32;
  constexpr int NT = 32;                 // kslice = 1024 fixed
  __shared__ __align__(16) unsigned short lds[65536];   // 128 KB
  // A slot s: lds + s*8192 ; B slot s: lds + 32768 + s*8192   (elems)

  const int tid = threadIdx.x;
  const int lane = tid & 63;
  const int wave = tid >> 6;            // 0..7
  const int wm = wave >> 2, wn = wave & 3;
  const int l16 = lane & 15, lhi = lane >> 4;

  // XCD-aware bijective swizzle on the xy grid (nwg per z-slice % 8 == 0)
  const int nwg = gridDim.x * gridDim.y;
  const int lin = blockIdx.y * gridDim.x + blockIdx.x;
  const int cpx = nwg >> 3;
  const int swz = (lin & 7) * cpx + (lin >> 3);
  const int bx = swz % gridDim.x, by = swz / gridDim.x;
  const int bm = by * 256, bn = bx * 256;
  const int kbase = blockIdx.z * (NT * BK);

  f32x4 acc[8][4] = {};

  // staging: per matrix per tile = 256x32x2B = 16 KB = 512thr x 16B x 2 rounds
  // dest linear (tid*8 + rr*4096); source chunk pre-swizzled by row&3.
  const int srow = tid >> 2;                         // 0..127
  const int scol = ((tid & 3) ^ (srow & 3)) * 8;     // swizzled source col

  auto stageA = [&](int tt) {
    unsigned short* dst = lds + (tt & 3) * 8192;
    const int kof = kbase + tt * BK;
#pragma unroll
    for (int rr = 0; rr < 2; ++rr)
      __builtin_amdgcn_global_load_lds(
          (const __attribute__((address_space(1))) void*)(Ag + (size_t)(bm + srow + rr * 128) * K + kof + scol),
          (__attribute__((address_space(3))) void*)(dst + tid * 8 + rr * 4096), 16, 0, 0);
  };
  auto stageB = [&](int tt) {
    unsigned short* dst = lds + 32768 + (tt & 3) * 8192;
    const int kof = kbase + tt * BK;
#pragma unroll
    for (int rr = 0; rr < 2; ++rr)
      __builtin_amdgcn_global_load_lds(
          (const __attribute__((address_space(1))) void*)(Bg + (size_t)(bn + srow + rr * 128) * K + kof + scol),
          (__attribute__((address_space(3))) void*)(dst + tid * 8 + rr * 4096), 16, 0, 0);
  };

  // prologue: tiles 0,1,2 staged (A,B interleaved -> FIFO oldest = tile 0)
  stageA(0); stageB(0);
  stageA(1); stageB(1);
  stageA(2); stageB(2);

  for (int t = 0; t < NT; ++t) {
    // retire tile t's loads (leave up to 2 tiles = 8 loads in flight)
    if (t < NT - 2)       asm volatile("s_waitcnt vmcnt(8)" ::: "memory");
    else if (t == NT - 2) asm volatile("s_waitcnt vmcnt(4)" ::: "memory");
    else                  asm volatile("s_waitcnt vmcnt(0)" ::: "memory");
    __builtin_amdgcn_s_barrier();       // all waves' DMA for tile t visible
    asm volatile("" ::: "memory");

    const unsigned short* As = lds + (t & 3) * 8192;
    const unsigned short* Bs = lds + 32768 + (t & 3) * 8192;
    bf16x8 bfr[4], afr[4];

    // ---- phase 0: B frags + A frags (mi 0-3); stage A(t+3); 16 MFMA ----
#pragma unroll
    for (int ni = 0; ni < 4; ++ni) {
      const int r = wn * 64 + ni * 16 + l16;
      bfr[ni] = ldsr128(Bs + r * BK + ((lhi ^ (r & 3)) * 8));
    }
#pragma unroll
    for (int mi = 0; mi < 4; ++mi) {
      const int r = wm * 128 + mi * 16 + l16;
      afr[mi] = ldsr128(As + r * BK + ((lhi ^ (r & 3)) * 8));
    }
    if (t + 3 < NT) stageA(t + 3);      // writes slot (t-1)&3: reads done @ t-1 end-bar
    asm volatile("s_waitcnt lgkmcnt(0)" ::: "memory");
    __builtin_amdgcn_sched_barrier(0);
    __builtin_amdgcn_s_setprio(1);
#pragma unroll
    for (int mi = 0; mi < 4; ++mi)
#pragma unroll
      for (int ni = 0; ni < 4; ++ni)
        acc[mi][ni] = __builtin_amdgcn_mfma_f32_16x16x32_bf16(afr[mi], bfr[ni], acc[mi][ni], 0, 0, 0);
    __builtin_amdgcn_s_setprio(0);

    // ---- phase 1: A frags (mi 4-7); stage B(t+3); 16 MFMA ----
#pragma unroll
    for (int mi = 0; mi < 4; ++mi) {
      const int r = wm * 128 + 64 + mi * 16 + l16;
      afr[mi] = ldsr128(As + r * BK + ((lhi ^ (r & 3)) * 8));
    }
    if (t + 3 < NT) stageB(t + 3);
    asm volatile("s_waitcnt lgkmcnt(0)" ::: "memory");
    __builtin_amdgcn_sched_barrier(0);
    __builtin_amdgcn_s_setprio(1);
#pragma unroll
    for (int mi = 0; mi < 4; ++mi)
#pragma unroll
      for (int ni = 0; ni < 4; ++ni)
        acc[4 + mi][ni] = __builtin_amdgcn_mfma_f32_16x16x32_bf16(afr[mi], bfr[ni], acc[4 + mi][ni], 0, 0, 0);
    __builtin_amdgcn_s_setprio(0);

    asm volatile("" ::: "memory");
    __builtin_amdgcn_s_barrier();       // end-of-tile: no wave may stage ahead
    asm volatile("" ::: "memory");
  }

  if (EPI == 0) {
    // fused MoE epilogue -> bf16, repacked through the (now free) 128KB LDS
    // as a [256][256] ushort tile for fully-coalesced 16B stores.
#pragma unroll
    for (int mi = 0; mi < 8; ++mi) {
#pragma unroll
      for (int r = 0; r < 4; ++r) {
        const int rowl = wm * 128 + mi * 16 + lhi * 4 + r;    // 0..255
        const int row = bm + rowl;
        const float* mt = meta + (size_t)row * 16;
        const int e0 = (int)mt[0], e1 = (int)mt[1];
        const float w0 = mt[2], w1 = mt[3];
        const float4 l0 = *(const float4*)(mt + 4);
        const float4 l1 = *(const float4*)(mt + 8);
#pragma unroll
        for (int ni = 0; ni < 4; ++ni) {
          const int coll = wn * 64 + ni * 16 + l16;
          const int f = bn + coll;
          const float4 b0 = *(const float4*)(B2 + ((size_t)e0 * Fdim + f) * Rdim);
          const float4 b1 = *(const float4*)(B2 + ((size_t)e1 * Fdim + f) * Rdim);
          const float a = acc[mi][ni][r];
          const float lora0 = l0.x * b0.x + l0.y * b0.y + l0.z * b0.z + l0.w * b0.w;
          const float lora1 = l1.x * b1.x + l1.y * b1.y + l1.z * b1.z + l1.w * b1.w;
          const float gv = w0 * fmaxf(a + lora0, 0.f) + w1 * fmaxf(a + lora1, 0.f);
          lds[rowl * 256 + coll] = f2bf(gv);
        }
      }
    }
    __syncthreads();
    // coalesced copy out: 256 rows x 512B; 16 rounds x 512 thr x 16B
#pragma unroll
    for (int rnd = 0; rnd < 16; ++rnd) {
      const int idx = rnd * 512 + tid;
      const int rowl = idx >> 5;                // 0..255
      const int chk = idx & 31;                 // 16B chunk within 512B row
      *(bf16x8*)(outg + (size_t)(bm + rowl) * Fdim + bn + chk * 8) =
          *(const bf16x8*)(lds + rowl * 256 + chk * 8);
    }
  } else {
    // split-K partial: f32 atomic accumulate
#pragma unroll
    for (int mi = 0; mi < 8; ++mi)
#pragma unroll
      for (int ni = 0; ni < 4; ++ni)
#pragma unroll
        for (int r = 0; r < 4; ++r) {
          const int row = bm + wm * 128 + mi * 16 + lhi * 4 + r;
          const int col = bn + wn * 64 + ni * 16 + l16;
          unsafeAtomicAdd(&outf[(size_t)row * Ncols + col], acc[mi][ni][r]);
        }
  }
}

extern "C" void kernel_launch(void* const* d_in, const int* in_sizes, int n_in,
                              void* d_out, int out_size, void* d_ws, size_t ws_size,
                              hipStream_t stream) {
  const float* x  = (const float*)d_in[0];
  const float* Wg = (const float*)d_in[1];
  const float* bg = (const float*)d_in[2];
  const float* Wi = (const float*)d_in[3];
  const float* Wo = (const float*)d_in[4];
  const float* Aw = (const float*)d_in[5];
  const float* B2 = (const float*)d_in[6];
  float* out = (float*)d_out;

  // workspace layout (bf16 as ushort)
  unsigned short* xb  = (unsigned short*)d_ws;                 // [BSz][Ddim]   8 MB
  unsigned short* wib = xb  + (size_t)BSz  * Ddim;             // [Fdim][Ddim]  8 MB
  unsigned short* wob = wib + (size_t)Fdim * Ddim;             // [Ddim][Fdim]  8 MB
  unsigned short* g   = wob + (size_t)Ddim * Fdim;             // [BSz][Fdim]  32 MB
  float* meta = (float*)(g + (size_t)BSz * Fdim);              // [BSz][16]   256 KB

  zero_f32<<<BSz * Ddim / 4 / 256, 256, 0, stream>>>(out, BSz * Ddim / 4);

  const int n4x = BSz * Ddim / 4;   // == Fdim*Ddim/4 == Ddim*Fdim/4
  cvt_kernel<<<(n4x + 255) / 256, 256, 0, stream>>>(x,  xb,  n4x);
  cvt_kernel<<<(n4x + 255) / 256, 256, 0, stream>>>(Wi, wib, n4x);
  cvt_kernel<<<(n4x + 255) / 256, 256, 0, stream>>>(Wo, wob, n4x);

  router_kernel<<<BSz, 256, 0, stream>>>(x, Wg, bg, Aw, meta);

  // GEMM1: base = x * Wi^T, fused MoE epilogue -> g (bf16)
  // 256^2 tile, ring-4 pipeline, grid 16x16 = 256 blocks, K = 1024 (32 tiles)
  gemmring<0><<<dim3(Fdim / 256, BSz / 256, 1), 512, 0, stream>>>(
      xb, wib, Ddim, Fdim, meta, B2, g, nullptr);

  // GEMM2: out = g * Wo^T, split-K x4 (1024 each), f32 atomics
  // grid 4x16x4 = 256 blocks
  gemmring<1><<<dim3(Ddim / 256, BSz / 256, 4), 512, 0, stream>>>(
      g, wob, Fdim, Ddim, nullptr, nullptr, nullptr, out);
}